// Round 17
// baseline (3286.235 us; speedup 1.0000x reference)
//
#include <hip/hip_runtime.h>
#include <math.h>

#define B_   256
#define C_   2048
#define D_   192
#define EPSf 1e-5f
#define SP   193     // LDS chunk row stride (floats): bank = (ch+d)&31 -> conflict-free reads

// ---------------------------------------------------------------------------
// numpy pairwise helpers (validated bit-exact R5..R16).
// ---------------------------------------------------------------------------
__device__ __forceinline__ float pw96_sq_s(const float* a) {
    float r0 = 0.f, r1 = 0.f, r2 = 0.f, r3 = 0.f, r4 = 0.f, r5 = 0.f, r6 = 0.f, r7 = 0.f;
#pragma unroll
    for (int i = 0; i < 12; ++i) {
        r0 += __fmul_rn(a[8 * i + 0], a[8 * i + 0]);
        r1 += __fmul_rn(a[8 * i + 1], a[8 * i + 1]);
        r2 += __fmul_rn(a[8 * i + 2], a[8 * i + 2]);
        r3 += __fmul_rn(a[8 * i + 3], a[8 * i + 3]);
        r4 += __fmul_rn(a[8 * i + 4], a[8 * i + 4]);
        r5 += __fmul_rn(a[8 * i + 5], a[8 * i + 5]);
        r6 += __fmul_rn(a[8 * i + 6], a[8 * i + 6]);
        r7 += __fmul_rn(a[8 * i + 7], a[8 * i + 7]);
    }
    return ((r0 + r1) + (r2 + r3)) + ((r4 + r5) + (r6 + r7));
}

__device__ __forceinline__ float pw96_sum_s(const float* a) {
    float r0 = 0.f, r1 = 0.f, r2 = 0.f, r3 = 0.f, r4 = 0.f, r5 = 0.f, r6 = 0.f, r7 = 0.f;
#pragma unroll
    for (int i = 0; i < 12; ++i) {
        r0 += a[8 * i + 0]; r1 += a[8 * i + 1];
        r2 += a[8 * i + 2]; r3 += a[8 * i + 3];
        r4 += a[8 * i + 4]; r5 += a[8 * i + 5];
        r6 += a[8 * i + 6]; r7 += a[8 * i + 7];
    }
    return ((r0 + r1) + (r2 + r3)) + ((r4 + r5) + (r6 + r7));
}

// ---------------------------------------------------------------------------
// Fused kmeans: ONE sequential pass over x per Lloyd iteration.
// 1024 thr/block, 1 block/sample. 32 chunks of 64 channels (49 KB), LDS
// double-buffered. Threads >=256 = DMA crew (stream chunk j+1 while compute
// runs). Threads <256: A-dots (ch,k) d-ascending chains; t<64: argmin (+xs/
// pooled on iter 0); t in [64,256): B dim-owner chains, c-ascending, register
// chain continues across the 6 chunks of each Q=384 BLAS block.
// All FP consume orders bit-identical to the R16 PASS.
// ---------------------------------------------------------------------------
__global__ __launch_bounds__(1024) void kmeans_fused_kernel(const float* __restrict__ x,
                                                            float* __restrict__ pooled,
                                                            unsigned char* __restrict__ ids_out) {
    const int b = blockIdx.x, t = threadIdx.x;
    const float* X = x + (size_t)b * (C_ * (size_t)D_);

    __shared__ float buf[2][64 * SP];     // 98816 B
    __shared__ float cent[4][192];
    __shared__ float xs_s[C_];
    __shared__ float dotb[64][5];
    __shared__ float part[6][4][192];
    __shared__ float cs4v[4];
    __shared__ int   cnt[4];
    __shared__ int   changed;
    __shared__ unsigned char ids[C_];

    if (t < 192) {
        cent[0][t] = X[(size_t)0    * D_ + t];
        cent[1][t] = X[(size_t)512  * D_ + t];
        cent[2][t] = X[(size_t)1024 * D_ + t];
        cent[3][t] = X[(size_t)1536 * D_ + t];
    }
    ids[2 * t] = 255; ids[2 * t + 1] = 255;

    // prologue: stage chunk 0 into buf[0] (all threads, 3 float4 each)
    {
        const float4* xp = (const float4*)X;
        float4 v0 = xp[t], v1 = xp[t + 1024], v2 = xp[t + 2048];
        {
            const int fi = t, ch = fi / 48, dq = fi % 48;
            float* d = &buf[0][ch * SP + dq * 4];
            d[0] = v0.x; d[1] = v0.y; d[2] = v0.z; d[3] = v0.w;
        }
        {
            const int fi = t + 1024, ch = fi / 48, dq = fi % 48;
            float* d = &buf[0][ch * SP + dq * 4];
            d[0] = v1.x; d[1] = v1.y; d[2] = v1.z; d[3] = v1.w;
        }
        {
            const int fi = t + 2048, ch = fi / 48, dq = fi % 48;
            float* d = &buf[0][ch * SP + dq * 4];
            d[0] = v2.x; d[1] = v2.y; d[2] = v2.z; d[3] = v2.w;
        }
    }
    __syncthreads();

    for (int iter = 0;; ++iter) {
        if (t < 4) cs4v[t] = pw96_sq_s(cent[t]) + pw96_sq_s(cent[t] + 96);
        if (t == 0) changed = 0;
        int lc0 = 0, lc1 = 0, lc2 = 0, lc3 = 0, mych = 0;
        float s0 = 0.f, s1 = 0.f, s2 = 0.f, s3 = 0.f;   // B accumulators
        __syncthreads();

        int cur = 0;
        for (int j = 0; j < 32; ++j) {
            // ---- phase 1: DMA issue (t>=256) || A dots (t<256) ----
            float4 v0, v1, v2, v3;
            const int nxt = (j + 1) & 31;
            if (t >= 256) {
                const int tt = t - 256;
                const float4* xp = (const float4*)X + (size_t)nxt * 3072;
                v0 = xp[tt]; v1 = xp[tt + 768]; v2 = xp[tt + 1536]; v3 = xp[tt + 2304];
            } else {
                const int ch = t & 63, k = t >> 6;
                const float* row = &buf[cur][ch * SP];
                const float* ck  = cent[k];
                float acc = 0.f;
#pragma unroll 8
                for (int d = 0; d < 192; ++d) acc = fmaf(row[d], ck[d], acc);
                dotb[ch][k] = acc;
            }
            __syncthreads();

            // ---- phase 2: argmin (t<64) || DMA ds_write to buf[cur^1] ----
            if (t < 64) {
                const int gc = j * 64 + t;
                if (iter == 0) {
                    const float* row = &buf[cur][t * SP];
                    xs_s[gc] = pw96_sq_s(row) + pw96_sq_s(row + 96);
                    pooled[(size_t)b * C_ + gc] =
                        (pw96_sum_s(row) + pw96_sum_s(row + 96)) / 192.0f;
                }
                const float xv = xs_s[gc];
                const float e0 = (xv - 2.0f * dotb[t][0]) + cs4v[0];
                const float e1 = (xv - 2.0f * dotb[t][1]) + cs4v[1];
                const float e2 = (xv - 2.0f * dotb[t][2]) + cs4v[2];
                const float e3 = (xv - 2.0f * dotb[t][3]) + cs4v[3];
                int id = 0; float best = e0;
                if (e1 < best) { best = e1; id = 1; }
                if (e2 < best) { best = e2; id = 2; }
                if (e3 < best) { best = e3; id = 3; }
                lc0 += (id == 0); lc1 += (id == 1); lc2 += (id == 2); lc3 += (id == 3);
                mych |= (ids[gc] != (unsigned char)id);
                ids[gc] = (unsigned char)id;
            } else if (t >= 256) {
                const int tt = t - 256;
                float* bn = buf[cur ^ 1];
                {
                    const int fi = tt, ch = fi / 48, dq = fi % 48;
                    float* d = &bn[ch * SP + dq * 4];
                    d[0] = v0.x; d[1] = v0.y; d[2] = v0.z; d[3] = v0.w;
                }
                {
                    const int fi = tt + 768, ch = fi / 48, dq = fi % 48;
                    float* d = &bn[ch * SP + dq * 4];
                    d[0] = v1.x; d[1] = v1.y; d[2] = v1.z; d[3] = v1.w;
                }
                {
                    const int fi = tt + 1536, ch = fi / 48, dq = fi % 48;
                    float* d = &bn[ch * SP + dq * 4];
                    d[0] = v2.x; d[1] = v2.y; d[2] = v2.z; d[3] = v2.w;
                }
                {
                    const int fi = tt + 2304, ch = fi / 48, dq = fi % 48;
                    float* d = &bn[ch * SP + dq * 4];
                    d[0] = v3.x; d[1] = v3.y; d[2] = v3.z; d[3] = v3.w;
                }
            }
            __syncthreads();

            // ---- phase 3: B (t in [64,256)): dim d adds 64 channels asc. ----
            if (t >= 64 && t < 256) {
                const int d = t - 64;
                const float* col = &buf[cur][d];
                const int cb = j * 64;
#pragma unroll 8
                for (int ch = 0; ch < 64; ++ch) {
                    const float xv = col[ch * SP];
                    const int id = ids[cb + ch];
                    s0 += (id == 0) ? xv : 0.0f;
                    s1 += (id == 1) ? xv : 0.0f;
                    s2 += (id == 2) ? xv : 0.0f;
                    s3 += (id == 3) ? xv : 0.0f;
                }
                if (j == 5 || j == 11 || j == 17 || j == 23 || j == 29 || j == 31) {
                    const int kb = j / 6;          // 31/6 = 5 (last block, 128 ch)
                    part[kb][0][d] = s0; part[kb][1][d] = s1;
                    part[kb][2][d] = s2; part[kb][3][d] = s3;
                    s0 = s1 = s2 = s3 = 0.f;
                }
            }
            __syncthreads();
            cur ^= 1;
        }

        // counts (t<64 is exactly wave 0) + changed flag
        if (t < 64) {
#pragma unroll
            for (int off = 32; off > 0; off >>= 1) {
                lc0 += __shfl_down(lc0, off);
                lc1 += __shfl_down(lc1, off);
                lc2 += __shfl_down(lc2, off);
                lc3 += __shfl_down(lc3, off);
            }
            if (t == 0) { cnt[0] = lc0; cnt[1] = lc1; cnt[2] = lc2; cnt[3] = lc3; }
            if (mych) changed = 1;
        }
        __syncthreads();

        if (changed == 0 || iter == 10) break;   // converged -> exact fixed point

        if (t < 192) {
#pragma unroll
            for (int k = 0; k < 4; ++k) {
                float tt = part[0][k][t];          // = 0 + p0 exactly (R5 order)
                tt += part[1][k][t];
                tt += part[2][k][t];
                tt += part[3][k][t];
                tt += part[4][k][t];
                tt += part[5][k][t];
                if (cnt[k] > 0) cent[k][t] = tt / (float)cnt[k];
            }
        }
        __syncthreads();
    }

    *(uchar2*)(ids_out + (size_t)b * C_ + 2 * t) = *(uchar2*)&ids[2 * t];
}

// ---------------------------------------------------------------------------
__device__ __forceinline__ float bn_apply(float v, float g, float be, float m, float va) {
    return (v - m) / sqrtf(va + EPSf) * g + be;
}

// ---------------------------------------------------------------------------
// Kernel 3: batched 64x64-tiled GEMM, M=256, N=512, K=2048.
// ---------------------------------------------------------------------------
__global__ __launch_bounds__(256) void gemm1_kernel(
    const float* __restrict__ pooled, const unsigned char* __restrict__ ids,
    const float* __restrict__ Wg, const float* __restrict__ bg,
    const float* __restrict__ g_gamma, const float* __restrict__ g_beta,
    const float* __restrict__ g_mean, const float* __restrict__ g_var,
    const float* __restrict__ gb_gamma, const float* __restrict__ gb_beta,
    const float* __restrict__ gb_mean, const float* __restrict__ gb_var,
    const float* __restrict__ W1, const float* __restrict__ b1,
    const float* __restrict__ n1_gamma, const float* __restrict__ n1_beta,
    const float* __restrict__ n1_mean, const float* __restrict__ n1_var,
    float* __restrict__ xg2, float* __restrict__ h1) {
    const int z = blockIdx.z;
    const int bn0 = blockIdx.x * 64, bm0 = blockIdx.y * 64;
    const float* Bmat = (z == 0) ? Wg : W1;
    __shared__ float As[32][68];
    __shared__ float Bs[32][68];
    float acc[4][4] = {};
    const int t = threadIdx.x;
    const int tx = t & 15, ty = t >> 4;

    for (int k0 = 0; k0 < 2048; k0 += 32) {
#pragma unroll
        for (int u = 0; u < 2; ++u) {
            const int idx = t + 256 * u;
            const int m = idx >> 3, kc = idx & 7;
            float4 v = *(const float4*)(pooled + (size_t)(bm0 + m) * 2048 + k0 + kc * 4);
            if (z > 0) {
                const unsigned int uu =
                    *(const unsigned int*)(ids + (size_t)(bm0 + m) * 2048 + k0 + kc * 4);
                const unsigned int k = (unsigned int)(z - 1);
                v.x = ((uu & 0xffu) == k) ? v.x : 0.f;
                v.y = (((uu >> 8) & 0xffu) == k) ? v.y : 0.f;
                v.z = (((uu >> 16) & 0xffu) == k) ? v.z : 0.f;
                v.w = (((uu >> 24) & 0xffu) == k) ? v.w : 0.f;
            }
            As[kc * 4 + 0][m] = v.x; As[kc * 4 + 1][m] = v.y;
            As[kc * 4 + 2][m] = v.z; As[kc * 4 + 3][m] = v.w;
            const float4 wv = *(const float4*)(Bmat + (size_t)(bn0 + m) * 2048 + k0 + kc * 4);
            Bs[kc * 4 + 0][m] = wv.x; Bs[kc * 4 + 1][m] = wv.y;
            Bs[kc * 4 + 2][m] = wv.z; Bs[kc * 4 + 3][m] = wv.w;
        }
        __syncthreads();
#pragma unroll 8
        for (int kk = 0; kk < 32; ++kk) {
            const float4 a = *(const float4*)&As[kk][ty * 4];
            const float4 wv = *(const float4*)&Bs[kk][tx * 4];
            const float av[4] = {a.x, a.y, a.z, a.w};
            const float bv[4] = {wv.x, wv.y, wv.z, wv.w};
#pragma unroll
            for (int i = 0; i < 4; ++i)
#pragma unroll
                for (int j = 0; j < 4; ++j) acc[i][j] += av[i] * bv[j];
        }
        __syncthreads();
    }

    const int m0 = bm0 + ty * 4, n0 = bn0 + tx * 4;
    if (z == 0) {
#pragma unroll
        for (int j = 0; j < 4; ++j) {
            const int n = n0 + j;
            const float bgv = bg[n];
            const float g1 = g_gamma[n], be1 = g_beta[n], mm1 = g_mean[n], vv1 = g_var[n];
            const float g2 = gb_gamma[n], be2 = gb_beta[n], mm2 = gb_mean[n], vv2 = gb_var[n];
#pragma unroll
            for (int i = 0; i < 4; ++i) {
                float v = acc[i][j] + bgv;
                v = bn_apply(v, g1, be1, mm1, vv1);
                v = fmaxf(v, 0.f);
                v = bn_apply(v, g2, be2, mm2, vv2);
                xg2[(size_t)(m0 + i) * 512 + n] = v;
            }
        }
    } else {
        const int k = z - 1;
#pragma unroll
        for (int j = 0; j < 4; ++j) {
            const int n = n0 + j;
            const float b1v = b1[n];
            const float g1 = n1_gamma[n], be1 = n1_beta[n], mm1 = n1_mean[n], vv1 = n1_var[n];
#pragma unroll
            for (int i = 0; i < 4; ++i) {
                float v = acc[i][j] + b1v;
                v = bn_apply(v, g1, be1, mm1, vv1);
                v = fmaxf(v, 0.f);
                h1[((size_t)k * 256 + (m0 + i)) * 512 + n] = v;
            }
        }
    }
}

// ---------------------------------------------------------------------------
// Kernel 4
// ---------------------------------------------------------------------------
__global__ __launch_bounds__(256) void gemm2_kernel(
    const float* __restrict__ h1, const float* __restrict__ W2,
    const float* __restrict__ b2,
    const float* __restrict__ n2_gamma, const float* __restrict__ n2_beta,
    const float* __restrict__ n2_mean, const float* __restrict__ n2_var,
    const float* __restrict__ bk_gamma, const float* __restrict__ bk_beta,
    const float* __restrict__ bk_mean, const float* __restrict__ bk_var,
    float* __restrict__ yv) {
    const int bn0 = blockIdx.x * 64, bm0 = blockIdx.y * 64;
    __shared__ float As[32][68];
    __shared__ float Bs[32][68];
    float acc[4][4] = {};
    const int t = threadIdx.x;
    const int tx = t & 15, ty = t >> 4;

    for (int k0 = 0; k0 < 512; k0 += 32) {
#pragma unroll
        for (int u = 0; u < 2; ++u) {
            const int idx = t + 256 * u;
            const int m = idx >> 3, kc = idx & 7;
            const float4 v = *(const float4*)(h1 + (size_t)(bm0 + m) * 512 + k0 + kc * 4);
            As[kc * 4 + 0][m] = v.x; As[kc * 4 + 1][m] = v.y;
            As[kc * 4 + 2][m] = v.z; As[kc * 4 + 3][m] = v.w;
            const float4 wv = *(const float4*)(W2 + (size_t)(bn0 + m) * 512 + k0 + kc * 4);
            Bs[kc * 4 + 0][m] = wv.x; Bs[kc * 4 + 1][m] = wv.y;
            Bs[kc * 4 + 2][m] = wv.z; Bs[kc * 4 + 3][m] = wv.w;
        }
        __syncthreads();
#pragma unroll 8
        for (int kk = 0; kk < 32; ++kk) {
            const float4 a = *(const float4*)&As[kk][ty * 4];
            const float4 wv = *(const float4*)&Bs[kk][tx * 4];
            const float av[4] = {a.x, a.y, a.z, a.w};
            const float bv[4] = {wv.x, wv.y, wv.z, wv.w};
#pragma unroll
            for (int i = 0; i < 4; ++i)
#pragma unroll
                for (int j = 0; j < 4; ++j) acc[i][j] += av[i] * bv[j];
        }
        __syncthreads();
    }

    const int m0 = bm0 + ty * 4, n0 = bn0 + tx * 4;
#pragma unroll
    for (int j = 0; j < 4; ++j) {
        const int n = n0 + j;
        const float b2v = b2[n];
        const float g1 = n2_gamma[n], be1 = n2_beta[n], mm1 = n2_mean[n], vv1 = n2_var[n];
#pragma unroll
        for (int i = 0; i < 4; ++i) {
            const int row = m0 + i;
            const int k = row >> 8, b = row & 255;
            float v = acc[i][j] + b2v;
            v = bn_apply(v, g1, be1, mm1, vv1);
            v = fmaxf(v, 0.f);
            const int pi = k * 128 + n;
            v = bn_apply(v, bk_gamma[pi], bk_beta[pi], bk_mean[pi], bk_var[pi]);
            yv[(size_t)b * 512 + pi] = v;
        }
    }
}

// ---------------------------------------------------------------------------
// Kernel 5: heads
// ---------------------------------------------------------------------------
__global__ __launch_bounds__(128) void head_kernel(
    const float* __restrict__ xg2, const float* __restrict__ yv,
    const float* __restrict__ Wcg, const float* __restrict__ bcg,
    const float* __restrict__ Wck, const float* __restrict__ bck,
    float* __restrict__ out) {
    const int b = blockIdx.x, t = threadIdx.x;
    __shared__ float xr[512], yr[512];
    ((float4*)xr)[t] = ((const float4*)(xg2 + (size_t)b * 512))[t];
    ((float4*)yr)[t] = ((const float4*)(yv + (size_t)b * 512))[t];
    __syncthreads();
    if (t < 51) {
        float acc = 0.f;
        const float4* wr = (const float4*)(Wcg + (size_t)t * 512);
        const float4* xv = (const float4*)xr;
#pragma unroll 8
        for (int p = 0; p < 128; ++p) {
            const float4 w4 = wr[p], v4 = xv[p];
            acc += w4.x * v4.x + w4.y * v4.y + w4.z * v4.z + w4.w * v4.w;
        }
        out[(size_t)b * 51 + t] = acc + bcg[t];
    } else if (t >= 64 && t < 115) {
        const int n = t - 64;
        float acc = 0.f;
        const float4* wr = (const float4*)(Wck + (size_t)n * 512);
        const float4* yv4 = (const float4*)yr;
#pragma unroll 8
        for (int p = 0; p < 128; ++p) {
            const float4 w4 = wr[p], v4 = yv4[p];
            acc += w4.x * v4.x + w4.y * v4.y + w4.z * v4.z + w4.w * v4.w;
        }
        out[(size_t)(B_ * 51) + (size_t)b * 51 + n] = acc + bck[n];
    }
}

// ---------------------------------------------------------------------------
extern "C" void kernel_launch(void* const* d_in, const int* in_sizes, int n_in,
                              void* d_out, int out_size, void* d_ws, size_t ws_size,
                              hipStream_t stream) {
    const float* x        = (const float*)d_in[0];
    const float* Wg       = (const float*)d_in[1];
    const float* bg       = (const float*)d_in[2];
    const float* g_gamma  = (const float*)d_in[3];
    const float* g_beta   = (const float*)d_in[4];
    const float* g_mean   = (const float*)d_in[5];
    const float* g_var    = (const float*)d_in[6];
    const float* gb_gamma = (const float*)d_in[7];
    const float* gb_beta  = (const float*)d_in[8];
    const float* gb_mean  = (const float*)d_in[9];
    const float* gb_var   = (const float*)d_in[10];
    const float* Wcg      = (const float*)d_in[11];
    const float* bcg      = (const float*)d_in[12];
    const float* W1       = (const float*)d_in[13];
    const float* b1       = (const float*)d_in[14];
    const float* n1_gamma = (const float*)d_in[15];
    const float* n1_beta  = (const float*)d_in[16];
    const float* n1_mean  = (const float*)d_in[17];
    const float* n1_var   = (const float*)d_in[18];
    const float* W2       = (const float*)d_in[19];
    const float* b2       = (const float*)d_in[20];
    const float* n2_gamma = (const float*)d_in[21];
    const float* n2_beta  = (const float*)d_in[22];
    const float* n2_mean  = (const float*)d_in[23];
    const float* n2_var   = (const float*)d_in[24];
    const float* bk_gamma = (const float*)d_in[25];
    const float* bk_beta  = (const float*)d_in[26];
    const float* bk_mean  = (const float*)d_in[27];
    const float* bk_var   = (const float*)d_in[28];
    const float* Wck      = (const float*)d_in[29];
    const float* bck      = (const float*)d_in[30];
    float* out = (float*)d_out;

    float* pooled      = (float*)d_ws;                       // 524288 f
    unsigned char* ids = (unsigned char*)(pooled + 524288);  // 524288 B
    float* xg2         = (float*)(ids + 524288);             // 131072 f
    float* h1          = xg2 + 131072;                       // 524288 f
    float* yv          = h1 + 524288;                        // 131072 f

    kmeans_fused_kernel<<<dim3(B_), dim3(1024), 0, stream>>>(x, pooled, ids);
    gemm1_kernel<<<dim3(8, 4, 5), dim3(256), 0, stream>>>(
        pooled, ids, Wg, bg, g_gamma, g_beta, g_mean, g_var,
        gb_gamma, gb_beta, gb_mean, gb_var, W1, b1,
        n1_gamma, n1_beta, n1_mean, n1_var, xg2, h1);
    gemm2_kernel<<<dim3(2, 16), dim3(256), 0, stream>>>(
        h1, W2, b2, n2_gamma, n2_beta, n2_mean, n2_var,
        bk_gamma, bk_beta, bk_mean, bk_var, yv);
    head_kernel<<<dim3(B_), dim3(128), 0, stream>>>(xg2, yv, Wcg, bcg, Wck, bck, out);
}

// Round 18
// 2346.232 us; speedup vs baseline: 1.4006x; 1.4006x over previous
//
#include <hip/hip_runtime.h>
#include <math.h>

#define B_   256
#define C_   2048
#define D_   192
#define EPSf 1e-5f
#define SP   196     // LDS chunk row stride: %4==0 (16B-aligned f4 ops), 196%32=4

// ---------------------------------------------------------------------------
// numpy pairwise helpers (validated bit-exact R5..R17).
// ---------------------------------------------------------------------------
__device__ __forceinline__ float pw96_sq_s(const float* a) {
    float r0 = 0.f, r1 = 0.f, r2 = 0.f, r3 = 0.f, r4 = 0.f, r5 = 0.f, r6 = 0.f, r7 = 0.f;
#pragma unroll
    for (int i = 0; i < 12; ++i) {
        r0 += __fmul_rn(a[8 * i + 0], a[8 * i + 0]);
        r1 += __fmul_rn(a[8 * i + 1], a[8 * i + 1]);
        r2 += __fmul_rn(a[8 * i + 2], a[8 * i + 2]);
        r3 += __fmul_rn(a[8 * i + 3], a[8 * i + 3]);
        r4 += __fmul_rn(a[8 * i + 4], a[8 * i + 4]);
        r5 += __fmul_rn(a[8 * i + 5], a[8 * i + 5]);
        r6 += __fmul_rn(a[8 * i + 6], a[8 * i + 6]);
        r7 += __fmul_rn(a[8 * i + 7], a[8 * i + 7]);
    }
    return ((r0 + r1) + (r2 + r3)) + ((r4 + r5) + (r6 + r7));
}

__device__ __forceinline__ float pw96_sum_s(const float* a) {
    float r0 = 0.f, r1 = 0.f, r2 = 0.f, r3 = 0.f, r4 = 0.f, r5 = 0.f, r6 = 0.f, r7 = 0.f;
#pragma unroll
    for (int i = 0; i < 12; ++i) {
        r0 += a[8 * i + 0]; r1 += a[8 * i + 1];
        r2 += a[8 * i + 2]; r3 += a[8 * i + 3];
        r4 += a[8 * i + 4]; r5 += a[8 * i + 5];
        r6 += a[8 * i + 6]; r7 += a[8 * i + 7];
    }
    return ((r0 + r1) + (r2 + r3)) + ((r4 + r5) + (r6 + r7));
}

// ---------------------------------------------------------------------------
// Fused kmeans (R18 = R17 design + perf fixes):
//  - DMA crew loads AND ds_writes inside phase 1 (no regs across barriers
//    -> no scratch spill; buf[cur^1] untouched by phases 1-3 of chunk j)
//  - SP=196: conflict-free float4 LDS writes + phase-1 float4 reads
//  - A-dot reads float4, consumes .x.y.z.w sequentially (R17 chain order)
// All FP consume orders bit-identical to the R17 PASS.
// ---------------------------------------------------------------------------
__global__ __launch_bounds__(1024) void kmeans_fused_kernel(const float* __restrict__ x,
                                                            float* __restrict__ pooled,
                                                            unsigned char* __restrict__ ids_out) {
    const int b = blockIdx.x, t = threadIdx.x;
    const float* X = x + (size_t)b * (C_ * (size_t)D_);

    __shared__ float buf[2][64 * SP];     // 100352 B
    __shared__ float cent[4][192];
    __shared__ float xs_s[C_];
    __shared__ float dotb[64][5];
    __shared__ float part[6][4][192];
    __shared__ float cs4v[4];
    __shared__ int   cnt[4];
    __shared__ int   changed;
    __shared__ unsigned char ids[C_];

    if (t < 192) {
        cent[0][t] = X[(size_t)0    * D_ + t];
        cent[1][t] = X[(size_t)512  * D_ + t];
        cent[2][t] = X[(size_t)1024 * D_ + t];
        cent[3][t] = X[(size_t)1536 * D_ + t];
    }
    ids[2 * t] = 255; ids[2 * t + 1] = 255;

    // prologue: stage chunk 0 into buf[0] (3072 float4, 3 per thread)
    {
        const float4* xp = (const float4*)X;
#pragma unroll
        for (int r = 0; r < 3; ++r) {
            const int fi = t + r * 1024;
            const float4 v = xp[fi];
            const int ch = fi / 48, dq = fi % 48;
            *(float4*)&buf[0][ch * SP + dq * 4] = v;
        }
    }
    __syncthreads();

    for (int iter = 0;; ++iter) {
        if (t < 4) cs4v[t] = pw96_sq_s(cent[t]) + pw96_sq_s(cent[t] + 96);
        if (t == 0) changed = 0;
        int lc0 = 0, lc1 = 0, lc2 = 0, lc3 = 0, mych = 0;
        float s0 = 0.f, s1 = 0.f, s2 = 0.f, s3 = 0.f;   // B accumulators
        __syncthreads();

        int cur = 0;
        for (int j = 0; j < 32; ++j) {
            // ---- phase 1: DMA load+write next chunk (t>=256) || A dots ----
            if (t >= 256) {
                const int tt = t - 256;
                const int nxt = (j + 1) & 31;
                const float4* xp = (const float4*)X + (size_t)nxt * 3072;
                float4 v0 = xp[tt], v1 = xp[tt + 768], v2 = xp[tt + 1536], v3 = xp[tt + 2304];
                float* bn = buf[cur ^ 1];
                {
                    const int fi = tt, ch = fi / 48, dq = fi % 48;
                    *(float4*)&bn[ch * SP + dq * 4] = v0;
                }
                {
                    const int fi = tt + 768, ch = fi / 48, dq = fi % 48;
                    *(float4*)&bn[ch * SP + dq * 4] = v1;
                }
                {
                    const int fi = tt + 1536, ch = fi / 48, dq = fi % 48;
                    *(float4*)&bn[ch * SP + dq * 4] = v2;
                }
                {
                    const int fi = tt + 2304, ch = fi / 48, dq = fi % 48;
                    *(float4*)&bn[ch * SP + dq * 4] = v3;
                }
            } else {
                const int ch = t & 63, k = t >> 6;
                const float4* row = (const float4*)&buf[cur][ch * SP];
                const float* ck  = cent[k];
                float acc = 0.f;
#pragma unroll 8
                for (int i = 0; i < 48; ++i) {
                    const float4 v = row[i];
                    acc = fmaf(v.x, ck[4 * i + 0], acc);
                    acc = fmaf(v.y, ck[4 * i + 1], acc);
                    acc = fmaf(v.z, ck[4 * i + 2], acc);
                    acc = fmaf(v.w, ck[4 * i + 3], acc);
                }
                dotb[ch][k] = acc;
            }
            __syncthreads();

            // ---- phase 2: argmin (t<64) (+ xs/pooled on iter 0) ----
            if (t < 64) {
                const int gc = j * 64 + t;
                if (iter == 0) {
                    const float* row = &buf[cur][t * SP];
                    xs_s[gc] = pw96_sq_s(row) + pw96_sq_s(row + 96);
                    pooled[(size_t)b * C_ + gc] =
                        (pw96_sum_s(row) + pw96_sum_s(row + 96)) / 192.0f;
                }
                const float xv = xs_s[gc];
                const float e0 = (xv - 2.0f * dotb[t][0]) + cs4v[0];
                const float e1 = (xv - 2.0f * dotb[t][1]) + cs4v[1];
                const float e2 = (xv - 2.0f * dotb[t][2]) + cs4v[2];
                const float e3 = (xv - 2.0f * dotb[t][3]) + cs4v[3];
                int id = 0; float best = e0;
                if (e1 < best) { best = e1; id = 1; }
                if (e2 < best) { best = e2; id = 2; }
                if (e3 < best) { best = e3; id = 3; }
                lc0 += (id == 0); lc1 += (id == 1); lc2 += (id == 2); lc3 += (id == 3);
                mych |= (ids[gc] != (unsigned char)id);
                ids[gc] = (unsigned char)id;
            }
            __syncthreads();

            // ---- phase 3: B (t in [64,256)): dim d adds 64 channels asc. ----
            if (t >= 64 && t < 256) {
                const int d = t - 64;
                const float* col = &buf[cur][d];
                const int cb = j * 64;
#pragma unroll 8
                for (int ch = 0; ch < 64; ++ch) {
                    const float xv = col[ch * SP];
                    const int id = ids[cb + ch];
                    s0 += (id == 0) ? xv : 0.0f;
                    s1 += (id == 1) ? xv : 0.0f;
                    s2 += (id == 2) ? xv : 0.0f;
                    s3 += (id == 3) ? xv : 0.0f;
                }
                if (j == 5 || j == 11 || j == 17 || j == 23 || j == 29 || j == 31) {
                    const int kb = j / 6;          // 31/6 = 5 (last block, 128 ch)
                    part[kb][0][d] = s0; part[kb][1][d] = s1;
                    part[kb][2][d] = s2; part[kb][3][d] = s3;
                    s0 = s1 = s2 = s3 = 0.f;
                }
            }
            __syncthreads();
            cur ^= 1;
        }

        // counts (t<64 is exactly wave 0) + changed flag
        if (t < 64) {
#pragma unroll
            for (int off = 32; off > 0; off >>= 1) {
                lc0 += __shfl_down(lc0, off);
                lc1 += __shfl_down(lc1, off);
                lc2 += __shfl_down(lc2, off);
                lc3 += __shfl_down(lc3, off);
            }
            if (t == 0) { cnt[0] = lc0; cnt[1] = lc1; cnt[2] = lc2; cnt[3] = lc3; }
            if (mych) changed = 1;
        }
        __syncthreads();

        if (changed == 0 || iter == 10) break;   // converged -> exact fixed point

        if (t < 192) {
#pragma unroll
            for (int k = 0; k < 4; ++k) {
                float tt = part[0][k][t];          // = 0 + p0 exactly (R5 order)
                tt += part[1][k][t];
                tt += part[2][k][t];
                tt += part[3][k][t];
                tt += part[4][k][t];
                tt += part[5][k][t];
                if (cnt[k] > 0) cent[k][t] = tt / (float)cnt[k];
            }
        }
        __syncthreads();
    }

    *(uchar2*)(ids_out + (size_t)b * C_ + 2 * t) = *(uchar2*)&ids[2 * t];
}

// ---------------------------------------------------------------------------
__device__ __forceinline__ float bn_apply(float v, float g, float be, float m, float va) {
    return (v - m) / sqrtf(va + EPSf) * g + be;
}

// ---------------------------------------------------------------------------
// Kernel 3: batched 64x64-tiled GEMM, M=256, N=512, K=2048.
// ---------------------------------------------------------------------------
__global__ __launch_bounds__(256) void gemm1_kernel(
    const float* __restrict__ pooled, const unsigned char* __restrict__ ids,
    const float* __restrict__ Wg, const float* __restrict__ bg,
    const float* __restrict__ g_gamma, const float* __restrict__ g_beta,
    const float* __restrict__ g_mean, const float* __restrict__ g_var,
    const float* __restrict__ gb_gamma, const float* __restrict__ gb_beta,
    const float* __restrict__ gb_mean, const float* __restrict__ gb_var,
    const float* __restrict__ W1, const float* __restrict__ b1,
    const float* __restrict__ n1_gamma, const float* __restrict__ n1_beta,
    const float* __restrict__ n1_mean, const float* __restrict__ n1_var,
    float* __restrict__ xg2, float* __restrict__ h1) {
    const int z = blockIdx.z;
    const int bn0 = blockIdx.x * 64, bm0 = blockIdx.y * 64;
    const float* Bmat = (z == 0) ? Wg : W1;
    __shared__ float As[32][68];
    __shared__ float Bs[32][68];
    float acc[4][4] = {};
    const int t = threadIdx.x;
    const int tx = t & 15, ty = t >> 4;

    for (int k0 = 0; k0 < 2048; k0 += 32) {
#pragma unroll
        for (int u = 0; u < 2; ++u) {
            const int idx = t + 256 * u;
            const int m = idx >> 3, kc = idx & 7;
            float4 v = *(const float4*)(pooled + (size_t)(bm0 + m) * 2048 + k0 + kc * 4);
            if (z > 0) {
                const unsigned int uu =
                    *(const unsigned int*)(ids + (size_t)(bm0 + m) * 2048 + k0 + kc * 4);
                const unsigned int k = (unsigned int)(z - 1);
                v.x = ((uu & 0xffu) == k) ? v.x : 0.f;
                v.y = (((uu >> 8) & 0xffu) == k) ? v.y : 0.f;
                v.z = (((uu >> 16) & 0xffu) == k) ? v.z : 0.f;
                v.w = (((uu >> 24) & 0xffu) == k) ? v.w : 0.f;
            }
            As[kc * 4 + 0][m] = v.x; As[kc * 4 + 1][m] = v.y;
            As[kc * 4 + 2][m] = v.z; As[kc * 4 + 3][m] = v.w;
            const float4 wv = *(const float4*)(Bmat + (size_t)(bn0 + m) * 2048 + k0 + kc * 4);
            Bs[kc * 4 + 0][m] = wv.x; Bs[kc * 4 + 1][m] = wv.y;
            Bs[kc * 4 + 2][m] = wv.z; Bs[kc * 4 + 3][m] = wv.w;
        }
        __syncthreads();
#pragma unroll 8
        for (int kk = 0; kk < 32; ++kk) {
            const float4 a = *(const float4*)&As[kk][ty * 4];
            const float4 wv = *(const float4*)&Bs[kk][tx * 4];
            const float av[4] = {a.x, a.y, a.z, a.w};
            const float bv[4] = {wv.x, wv.y, wv.z, wv.w};
#pragma unroll
            for (int i = 0; i < 4; ++i)
#pragma unroll
                for (int j = 0; j < 4; ++j) acc[i][j] += av[i] * bv[j];
        }
        __syncthreads();
    }

    const int m0 = bm0 + ty * 4, n0 = bn0 + tx * 4;
    if (z == 0) {
#pragma unroll
        for (int j = 0; j < 4; ++j) {
            const int n = n0 + j;
            const float bgv = bg[n];
            const float g1 = g_gamma[n], be1 = g_beta[n], mm1 = g_mean[n], vv1 = g_var[n];
            const float g2 = gb_gamma[n], be2 = gb_beta[n], mm2 = gb_mean[n], vv2 = gb_var[n];
#pragma unroll
            for (int i = 0; i < 4; ++i) {
                float v = acc[i][j] + bgv;
                v = bn_apply(v, g1, be1, mm1, vv1);
                v = fmaxf(v, 0.f);
                v = bn_apply(v, g2, be2, mm2, vv2);
                xg2[(size_t)(m0 + i) * 512 + n] = v;
            }
        }
    } else {
        const int k = z - 1;
#pragma unroll
        for (int j = 0; j < 4; ++j) {
            const int n = n0 + j;
            const float b1v = b1[n];
            const float g1 = n1_gamma[n], be1 = n1_beta[n], mm1 = n1_mean[n], vv1 = n1_var[n];
#pragma unroll
            for (int i = 0; i < 4; ++i) {
                float v = acc[i][j] + b1v;
                v = bn_apply(v, g1, be1, mm1, vv1);
                v = fmaxf(v, 0.f);
                h1[((size_t)k * 256 + (m0 + i)) * 512 + n] = v;
            }
        }
    }
}

// ---------------------------------------------------------------------------
// Kernel 4
// ---------------------------------------------------------------------------
__global__ __launch_bounds__(256) void gemm2_kernel(
    const float* __restrict__ h1, const float* __restrict__ W2,
    const float* __restrict__ b2,
    const float* __restrict__ n2_gamma, const float* __restrict__ n2_beta,
    const float* __restrict__ n2_mean, const float* __restrict__ n2_var,
    const float* __restrict__ bk_gamma, const float* __restrict__ bk_beta,
    const float* __restrict__ bk_mean, const float* __restrict__ bk_var,
    float* __restrict__ yv) {
    const int bn0 = blockIdx.x * 64, bm0 = blockIdx.y * 64;
    __shared__ float As[32][68];
    __shared__ float Bs[32][68];
    float acc[4][4] = {};
    const int t = threadIdx.x;
    const int tx = t & 15, ty = t >> 4;

    for (int k0 = 0; k0 < 512; k0 += 32) {
#pragma unroll
        for (int u = 0; u < 2; ++u) {
            const int idx = t + 256 * u;
            const int m = idx >> 3, kc = idx & 7;
            const float4 v = *(const float4*)(h1 + (size_t)(bm0 + m) * 512 + k0 + kc * 4);
            As[kc * 4 + 0][m] = v.x; As[kc * 4 + 1][m] = v.y;
            As[kc * 4 + 2][m] = v.z; As[kc * 4 + 3][m] = v.w;
            const float4 wv = *(const float4*)(W2 + (size_t)(bn0 + m) * 512 + k0 + kc * 4);
            Bs[kc * 4 + 0][m] = wv.x; Bs[kc * 4 + 1][m] = wv.y;
            Bs[kc * 4 + 2][m] = wv.z; Bs[kc * 4 + 3][m] = wv.w;
        }
        __syncthreads();
#pragma unroll 8
        for (int kk = 0; kk < 32; ++kk) {
            const float4 a = *(const float4*)&As[kk][ty * 4];
            const float4 wv = *(const float4*)&Bs[kk][tx * 4];
            const float av[4] = {a.x, a.y, a.z, a.w};
            const float bv[4] = {wv.x, wv.y, wv.z, wv.w};
#pragma unroll
            for (int i = 0; i < 4; ++i)
#pragma unroll
                for (int j = 0; j < 4; ++j) acc[i][j] += av[i] * bv[j];
        }
        __syncthreads();
    }

    const int m0 = bm0 + ty * 4, n0 = bn0 + tx * 4;
#pragma unroll
    for (int j = 0; j < 4; ++j) {
        const int n = n0 + j;
        const float b2v = b2[n];
        const float g1 = n2_gamma[n], be1 = n2_beta[n], mm1 = n2_mean[n], vv1 = n2_var[n];
#pragma unroll
        for (int i = 0; i < 4; ++i) {
            const int row = m0 + i;
            const int k = row >> 8, b = row & 255;
            float v = acc[i][j] + b2v;
            v = bn_apply(v, g1, be1, mm1, vv1);
            v = fmaxf(v, 0.f);
            const int pi = k * 128 + n;
            v = bn_apply(v, bk_gamma[pi], bk_beta[pi], bk_mean[pi], bk_var[pi]);
            yv[(size_t)b * 512 + pi] = v;
        }
    }
}

// ---------------------------------------------------------------------------
// Kernel 5: heads
// ---------------------------------------------------------------------------
__global__ __launch_bounds__(128) void head_kernel(
    const float* __restrict__ xg2, const float* __restrict__ yv,
    const float* __restrict__ Wcg, const float* __restrict__ bcg,
    const float* __restrict__ Wck, const float* __restrict__ bck,
    float* __restrict__ out) {
    const int b = blockIdx.x, t = threadIdx.x;
    __shared__ float xr[512], yr[512];
    ((float4*)xr)[t] = ((const float4*)(xg2 + (size_t)b * 512))[t];
    ((float4*)yr)[t] = ((const float4*)(yv + (size_t)b * 512))[t];
    __syncthreads();
    if (t < 51) {
        float acc = 0.f;
        const float4* wr = (const float4*)(Wcg + (size_t)t * 512);
        const float4* xv = (const float4*)xr;
#pragma unroll 8
        for (int p = 0; p < 128; ++p) {
            const float4 w4 = wr[p], v4 = xv[p];
            acc += w4.x * v4.x + w4.y * v4.y + w4.z * v4.z + w4.w * v4.w;
        }
        out[(size_t)b * 51 + t] = acc + bcg[t];
    } else if (t >= 64 && t < 115) {
        const int n = t - 64;
        float acc = 0.f;
        const float4* wr = (const float4*)(Wck + (size_t)n * 512);
        const float4* yv4 = (const float4*)yr;
#pragma unroll 8
        for (int p = 0; p < 128; ++p) {
            const float4 w4 = wr[p], v4 = yv4[p];
            acc += w4.x * v4.x + w4.y * v4.y + w4.z * v4.z + w4.w * v4.w;
        }
        out[(size_t)(B_ * 51) + (size_t)b * 51 + n] = acc + bck[n];
    }
}

// ---------------------------------------------------------------------------
extern "C" void kernel_launch(void* const* d_in, const int* in_sizes, int n_in,
                              void* d_out, int out_size, void* d_ws, size_t ws_size,
                              hipStream_t stream) {
    const float* x        = (const float*)d_in[0];
    const float* Wg       = (const float*)d_in[1];
    const float* bg       = (const float*)d_in[2];
    const float* g_gamma  = (const float*)d_in[3];
    const float* g_beta   = (const float*)d_in[4];
    const float* g_mean   = (const float*)d_in[5];
    const float* g_var    = (const float*)d_in[6];
    const float* gb_gamma = (const float*)d_in[7];
    const float* gb_beta  = (const float*)d_in[8];
    const float* gb_mean  = (const float*)d_in[9];
    const float* gb_var   = (const float*)d_in[10];
    const float* Wcg      = (const float*)d_in[11];
    const float* bcg      = (const float*)d_in[12];
    const float* W1       = (const float*)d_in[13];
    const float* b1       = (const float*)d_in[14];
    const float* n1_gamma = (const float*)d_in[15];
    const float* n1_beta  = (const float*)d_in[16];
    const float* n1_mean  = (const float*)d_in[17];
    const float* n1_var   = (const float*)d_in[18];
    const float* W2       = (const float*)d_in[19];
    const float* b2       = (const float*)d_in[20];
    const float* n2_gamma = (const float*)d_in[21];
    const float* n2_beta  = (const float*)d_in[22];
    const float* n2_mean  = (const float*)d_in[23];
    const float* n2_var   = (const float*)d_in[24];
    const float* bk_gamma = (const float*)d_in[25];
    const float* bk_beta  = (const float*)d_in[26];
    const float* bk_mean  = (const float*)d_in[27];
    const float* bk_var   = (const float*)d_in[28];
    const float* Wck      = (const float*)d_in[29];
    const float* bck      = (const float*)d_in[30];
    float* out = (float*)d_out;

    float* pooled      = (float*)d_ws;                       // 524288 f
    unsigned char* ids = (unsigned char*)(pooled + 524288);  // 524288 B
    float* xg2         = (float*)(ids + 524288);             // 131072 f
    float* h1          = xg2 + 131072;                       // 524288 f
    float* yv          = h1 + 524288;                        // 131072 f

    kmeans_fused_kernel<<<dim3(B_), dim3(1024), 0, stream>>>(x, pooled, ids);
    gemm1_kernel<<<dim3(8, 4, 5), dim3(256), 0, stream>>>(
        pooled, ids, Wg, bg, g_gamma, g_beta, g_mean, g_var,
        gb_gamma, gb_beta, gb_mean, gb_var, W1, b1,
        n1_gamma, n1_beta, n1_mean, n1_var, xg2, h1);
    gemm2_kernel<<<dim3(2, 16), dim3(256), 0, stream>>>(
        h1, W2, b2, n2_gamma, n2_beta, n2_mean, n2_var,
        bk_gamma, bk_beta, bk_mean, bk_var, yv);
    head_kernel<<<dim3(B_), dim3(128), 0, stream>>>(xg2, yv, Wcg, bcg, Wck, bck, out);
}

// Round 19
// 1755.063 us; speedup vs baseline: 1.8724x; 1.3368x over previous
//
#include <hip/hip_runtime.h>
#include <math.h>

#define B_    256
#define C_    2048
#define C_PAD 2112   // padded xT row stride (8448 B, non-pow2)
#define D_    192
#define EPSf  1e-5f
#define BLAS_Q 384   // OpenBLAS SGEMM_DEFAULT_Q — K-block size (validated in R5)

// ---------------------------------------------------------------------------
// numpy pairwise helpers (validated bit-exact in R5..R16).
// ---------------------------------------------------------------------------
__device__ __forceinline__ float pw96_sq_f4(const float4* a4) {
    float r0 = 0.f, r1 = 0.f, r2 = 0.f, r3 = 0.f, r4 = 0.f, r5 = 0.f, r6 = 0.f, r7 = 0.f;
#pragma unroll
    for (int i = 0; i < 12; ++i) {
        const float4 v0 = a4[2 * i], v1 = a4[2 * i + 1];
        r0 += __fmul_rn(v0.x, v0.x); r1 += __fmul_rn(v0.y, v0.y);
        r2 += __fmul_rn(v0.z, v0.z); r3 += __fmul_rn(v0.w, v0.w);
        r4 += __fmul_rn(v1.x, v1.x); r5 += __fmul_rn(v1.y, v1.y);
        r6 += __fmul_rn(v1.z, v1.z); r7 += __fmul_rn(v1.w, v1.w);
    }
    return ((r0 + r1) + (r2 + r3)) + ((r4 + r5) + (r6 + r7));
}

__device__ __forceinline__ float pw96_sq_s(const float* a) {
    float r0 = 0.f, r1 = 0.f, r2 = 0.f, r3 = 0.f, r4 = 0.f, r5 = 0.f, r6 = 0.f, r7 = 0.f;
#pragma unroll
    for (int i = 0; i < 12; ++i) {
        r0 += __fmul_rn(a[8 * i + 0], a[8 * i + 0]);
        r1 += __fmul_rn(a[8 * i + 1], a[8 * i + 1]);
        r2 += __fmul_rn(a[8 * i + 2], a[8 * i + 2]);
        r3 += __fmul_rn(a[8 * i + 3], a[8 * i + 3]);
        r4 += __fmul_rn(a[8 * i + 4], a[8 * i + 4]);
        r5 += __fmul_rn(a[8 * i + 5], a[8 * i + 5]);
        r6 += __fmul_rn(a[8 * i + 6], a[8 * i + 6]);
        r7 += __fmul_rn(a[8 * i + 7], a[8 * i + 7]);
    }
    return ((r0 + r1) + (r2 + r3)) + ((r4 + r5) + (r6 + r7));
}

__device__ __forceinline__ float pw96_sum_s(const float* a) {
    float r0 = 0.f, r1 = 0.f, r2 = 0.f, r3 = 0.f, r4 = 0.f, r5 = 0.f, r6 = 0.f, r7 = 0.f;
#pragma unroll
    for (int i = 0; i < 12; ++i) {
        r0 += a[8 * i + 0]; r1 += a[8 * i + 1];
        r2 += a[8 * i + 2]; r3 += a[8 * i + 3];
        r4 += a[8 * i + 4]; r5 += a[8 * i + 5];
        r6 += a[8 * i + 6]; r7 += a[8 * i + 7];
    }
    return ((r0 + r1) + (r2 + r3)) + ((r4 + r5) + (r6 + r7));
}

// ---------------------------------------------------------------------------
// Kernel 0: fused transpose + xs + pooled (validated R14/R16).
// ---------------------------------------------------------------------------
__global__ __launch_bounds__(256) void transpose_kernel(const float* __restrict__ x,
                                                        float* __restrict__ xT,
                                                        float* __restrict__ pooled,
                                                        float* __restrict__ xs_g) {
    const int c0 = blockIdx.x * 64, b = blockIdx.y;
    const float* X = x + (size_t)b * (C_ * (size_t)D_);
    float* XT      = xT + (size_t)b * ((size_t)D_ * C_PAD);
    __shared__ float lds[64 * 193];
    const int t = threadIdx.x;

#pragma unroll
    for (int i = 0; i < 12; ++i) {
        const int idx = i * 256 + t;
        const int r = idx / 48, j = idx % 48;
        const float4 v = *(const float4*)(X + (size_t)(c0 + r) * D_ + 4 * j);
        float* p = &lds[r * 193 + 4 * j];
        p[0] = v.x; p[1] = v.y; p[2] = v.z; p[3] = v.w;
    }
    __syncthreads();

    if (t < 64) {
        const float* row = &lds[t * 193];
        xs_g[(size_t)b * C_ + c0 + t]   = pw96_sq_s(row)  + pw96_sq_s(row + 96);
        pooled[(size_t)b * C_ + c0 + t] = (pw96_sum_s(row) + pw96_sum_s(row + 96)) / 192.0f;
    }

#pragma unroll
    for (int i = 0; i < 48; ++i) {
        const int idx = i * 256 + t;
        const int d = idx >> 6, ch = idx & 63;
        XT[(size_t)d * C_PAD + c0 + ch] = lds[ch * 193 + d];
    }
}

// ---------------------------------------------------------------------------
// Batch-16 compute helpers (float2; FP chain order == R16 PASS)
// ---------------------------------------------------------------------------
__device__ __forceinline__ void pa_comp16_f2(const float2 (&vb)[16], int dbase,
                                             const float (*cent)[192],
                                             float (&acc)[2][4]) {
#pragma unroll
    for (int u = 0; u < 16; ++u) {
        const int d = dbase + u;
        const float c0 = cent[0][d], c1 = cent[1][d];
        const float c2 = cent[2][d], c3 = cent[3][d];
        acc[0][0] = fmaf(vb[u].x, c0, acc[0][0]);
        acc[1][0] = fmaf(vb[u].y, c0, acc[1][0]);
        acc[0][1] = fmaf(vb[u].x, c1, acc[0][1]);
        acc[1][1] = fmaf(vb[u].y, c1, acc[1][1]);
        acc[0][2] = fmaf(vb[u].x, c2, acc[0][2]);
        acc[1][2] = fmaf(vb[u].y, c2, acc[1][2]);
        acc[0][3] = fmaf(vb[u].x, c3, acc[0][3]);
        acc[1][3] = fmaf(vb[u].y, c3, acc[1][3]);
    }
}

__device__ __forceinline__ void pb_comp16_f2(const float2 (&vb)[16], int cbase,
                                             const unsigned char* ids,
                                             float (&s)[2][4]) {
#pragma unroll
    for (int u = 0; u < 16; ++u) {
        const int id = ids[cbase + u];
        s[0][0] += (id == 0) ? vb[u].x : 0.0f;
        s[1][0] += (id == 0) ? vb[u].y : 0.0f;
        s[0][1] += (id == 1) ? vb[u].x : 0.0f;
        s[1][1] += (id == 1) ? vb[u].y : 0.0f;
        s[0][2] += (id == 2) ? vb[u].x : 0.0f;
        s[1][2] += (id == 2) ? vb[u].y : 0.0f;
        s[0][3] += (id == 3) ? vb[u].x : 0.0f;
        s[1][3] += (id == 3) ? vb[u].y : 0.0f;
    }
}

// ---------------------------------------------------------------------------
// Kernel 1: kmeans, 1024 thr/block, 1 block/sample (R16-validated).
// ---------------------------------------------------------------------------
__global__ __launch_bounds__(1024) void kmeans_fast_kernel(const float* __restrict__ x,
                                                           const float* __restrict__ xT,
                                                           const float* __restrict__ xs_g,
                                                           unsigned char* __restrict__ ids_out) {
    const int b = blockIdx.x, t = threadIdx.x;
    const int lane = t & 63;
    const float* X   = x  + (size_t)b * (C_ * (size_t)D_);
    const float* XTb = xT + (size_t)b * ((size_t)D_ * C_PAD);

    __shared__ __align__(16) float cent[4][192];
    __shared__ float xs_s[C_];
    __shared__ float part[6][4][192];
    __shared__ float cs4[4];
    __shared__ int   cnt[4];
    __shared__ int   changed;
    __shared__ unsigned char ids[C_];

    if (t < 192) {
        cent[0][t] = X[(size_t)0    * D_ + t];
        cent[1][t] = X[(size_t)512  * D_ + t];
        cent[2][t] = X[(size_t)1024 * D_ + t];
        cent[3][t] = X[(size_t)1536 * D_ + t];
    }
    {
        const int c2 = 2 * t;
        const float2 xv2 = *(const float2*)(xs_g + (size_t)b * C_ + c2);
        xs_s[c2] = xv2.x; xs_s[c2 + 1] = xv2.y;
        ids[c2] = 255; ids[c2 + 1] = 255;
    }
    __syncthreads();

    for (int iter = 0;; ++iter) {
        if (t < 4) {
            cs4[t] = pw96_sq_s(cent[t]) + pw96_sq_s(cent[t] + 96);
            cnt[t] = 0;
        }
        if (t == 0) changed = 0;
        __syncthreads();

        const float q0 = cs4[0], q1 = cs4[1], q2 = cs4[2], q3 = cs4[3];

        // ---- Phase A: channels 2t, 2t+1; batch-16 float2 loads (padded) ----
        int lc0 = 0, lc1 = 0, lc2 = 0, lc3 = 0, mych = 0;
        {
            const float2* pA = (const float2*)XTb + t;   // stride per d = C_PAD/2 f2
            float acc[2][4] = {};
            float2 buf[16];
            for (int db = 0; db < 192; db += 16) {
#pragma unroll
                for (int u = 0; u < 16; ++u) buf[u] = pA[(size_t)(db + u) * (C_PAD / 2)];
                pa_comp16_f2(buf, db, cent, acc);
            }
#pragma unroll
            for (int ch = 0; ch < 2; ++ch) {
                const int c = 2 * t + ch;
                const float xv = xs_s[c];
                const float e0 = (xv - 2.0f * acc[ch][0]) + q0;
                const float e1 = (xv - 2.0f * acc[ch][1]) + q1;
                const float e2 = (xv - 2.0f * acc[ch][2]) + q2;
                const float e3 = (xv - 2.0f * acc[ch][3]) + q3;
                int id = 0; float best = e0;
                if (e1 < best) { best = e1; id = 1; }
                if (e2 < best) { best = e2; id = 2; }
                if (e3 < best) { best = e3; id = 3; }
                lc0 += (id == 0); lc1 += (id == 1); lc2 += (id == 2); lc3 += (id == 3);
                mych |= (ids[c] != (unsigned char)id);
                ids[c] = (unsigned char)id;
            }
        }
#pragma unroll
        for (int off = 32; off > 0; off >>= 1) {
            lc0 += __shfl_down(lc0, off);
            lc1 += __shfl_down(lc1, off);
            lc2 += __shfl_down(lc2, off);
            lc3 += __shfl_down(lc3, off);
        }
        if (lane == 0) {
            atomicAdd(&cnt[0], lc0); atomicAdd(&cnt[1], lc1);
            atomicAdd(&cnt[2], lc2); atomicAdd(&cnt[3], lc3);
        }
        if (mych) changed = 1;
        __syncthreads();

        if (changed == 0 || iter == 10) break;   // converged -> exact fixed point

        // ---- Phase B: 576 tasks (kb, dim-pair); batch-16 float2;
        // per-(dim,k) chains ascend c within clamped Q=384 blocks. ----
        if (t < 576) {
            const int kb = t / 96;
            const int dg = t - kb * 96;           // dims 2dg, 2dg+1
            const int cb = kb * BLAS_Q;
            const int ce = (cb + BLAS_Q < C_) ? (cb + BLAS_Q) : C_;
            const int nc = ce - cb;               // 384 or 128 (both /16)
            const float2* pB = (const float2*)X + (size_t)cb * 96 + dg;
            float s[2][4] = {};
            float2 buf[16];
            for (int c0i = 0; c0i < nc; c0i += 16) {
#pragma unroll
                for (int u = 0; u < 16; ++u) buf[u] = pB[(size_t)(c0i + u) * 96];
                pb_comp16_f2(buf, cb + c0i, ids, s);
            }
#pragma unroll
            for (int k = 0; k < 4; ++k) {
                part[kb][k][2 * dg + 0] = s[0][k];
                part[kb][k][2 * dg + 1] = s[1][k];
            }
        }
        __syncthreads();
        if (t < 192) {
#pragma unroll
            for (int k = 0; k < 4; ++k) {
                float tt = part[0][k][t];          // = 0 + p0 exactly (R5 order)
                tt += part[1][k][t];
                tt += part[2][k][t];
                tt += part[3][k][t];
                tt += part[4][k][t];
                tt += part[5][k][t];
                if (cnt[k] > 0) cent[k][t] = tt / (float)cnt[k];
            }
        }
        __syncthreads();
    }

    *(uchar2*)(ids_out + (size_t)b * C_ + 2 * t) = *(uchar2*)&ids[2 * t];
}

// ---------------------------------------------------------------------------
// FALLBACK (ws too small): exact R8 PASS kernels.
// ---------------------------------------------------------------------------
__global__ __launch_bounds__(256) void pool_kernel(const float* __restrict__ x,
                                                   float* __restrict__ pooled) {
    const int row  = blockIdx.x * 4 + (threadIdx.x >> 6);
    const int lane = threadIdx.x & 63;
    const float* r = x + (size_t)row * D_;
    float s = 0.f;
    if (lane < 48) {
        const float4 v = ((const float4*)r)[lane];
        s = v.x + v.y + v.z + v.w;
    }
#pragma unroll
    for (int off = 32; off > 0; off >>= 1) s += __shfl_down(s, off);
    if (lane == 0) pooled[row] = s * (1.f / 192.f);
}

__global__ __launch_bounds__(512) void kmeans_fb_kernel(const float* __restrict__ x,
                                                        unsigned char* __restrict__ ids_out) {
    const int b = blockIdx.x, t = threadIdx.x;
    const int lane = t & 63;
    const float* X = x + (size_t)b * (C_ * (size_t)D_);

    __shared__ __align__(16) float cent[4][192];
    __shared__ float xs_s[C_];
    __shared__ float cs4[4];
    __shared__ int   cnt[4];
    __shared__ int   changed;
    __shared__ unsigned char ids[C_];

    if (t < 192) {
        cent[0][t] = X[(size_t)0    * D_ + t];
        cent[1][t] = X[(size_t)512  * D_ + t];
        cent[2][t] = X[(size_t)1024 * D_ + t];
        cent[3][t] = X[(size_t)1536 * D_ + t];
    }
    for (int c = t; c < C_; c += 512) {
        const float4* r4 = (const float4*)(X + (size_t)c * D_);
        xs_s[c] = pw96_sq_f4(r4) + pw96_sq_f4(r4 + 24);
        ids[c]  = 255;
    }
    __syncthreads();

    for (int iter = 0;; ++iter) {
        if (t < 4) {
            cs4[t] = pw96_sq_s(cent[t]) + pw96_sq_s(cent[t] + 96);
            cnt[t] = 0;
        }
        if (t == 0) changed = 0;
        __syncthreads();

        const float q0 = cs4[0], q1 = cs4[1], q2 = cs4[2], q3 = cs4[3];
        int lc0 = 0, lc1 = 0, lc2 = 0, lc3 = 0, mych = 0;
        for (int j = 0; j < 4; ++j) {
            const int c = t + 512 * j;
            const float4* r4 = (const float4*)(X + (size_t)c * D_);
            float d0 = 0.f, d1 = 0.f, d2 = 0.f, d3 = 0.f;
#pragma unroll 8
            for (int i = 0; i < 48; ++i) {
                const float4 a  = r4[i];
                const float4 c0 = *(const float4*)&cent[0][4 * i];
                const float4 c1 = *(const float4*)&cent[1][4 * i];
                const float4 c2 = *(const float4*)&cent[2][4 * i];
                const float4 c3 = *(const float4*)&cent[3][4 * i];
                d0 = fmaf(a.x, c0.x, d0); d0 = fmaf(a.y, c0.y, d0);
                d0 = fmaf(a.z, c0.z, d0); d0 = fmaf(a.w, c0.w, d0);
                d1 = fmaf(a.x, c1.x, d1); d1 = fmaf(a.y, c1.y, d1);
                d1 = fmaf(a.z, c1.z, d1); d1 = fmaf(a.w, c1.w, d1);
                d2 = fmaf(a.x, c2.x, d2); d2 = fmaf(a.y, c2.y, d2);
                d2 = fmaf(a.z, c2.z, d2); d2 = fmaf(a.w, c2.w, d2);
                d3 = fmaf(a.x, c3.x, d3); d3 = fmaf(a.y, c3.y, d3);
                d3 = fmaf(a.z, c3.z, d3); d3 = fmaf(a.w, c3.w, d3);
            }
            const float xv = xs_s[c];
            const float e0 = (xv - 2.0f * d0) + q0;
            const float e1 = (xv - 2.0f * d1) + q1;
            const float e2 = (xv - 2.0f * d2) + q2;
            const float e3 = (xv - 2.0f * d3) + q3;
            int id = 0; float best = e0;
            if (e1 < best) { best = e1; id = 1; }
            if (e2 < best) { best = e2; id = 2; }
            if (e3 < best) { best = e3; id = 3; }
            lc0 += (id == 0); lc1 += (id == 1); lc2 += (id == 2); lc3 += (id == 3);
            mych |= (ids[c] != (unsigned char)id);
            ids[c] = (unsigned char)id;
        }
#pragma unroll
        for (int off = 32; off > 0; off >>= 1) {
            lc0 += __shfl_down(lc0, off);
            lc1 += __shfl_down(lc1, off);
            lc2 += __shfl_down(lc2, off);
            lc3 += __shfl_down(lc3, off);
        }
        if (lane == 0) {
            atomicAdd(&cnt[0], lc0); atomicAdd(&cnt[1], lc1);
            atomicAdd(&cnt[2], lc2); atomicAdd(&cnt[3], lc3);
        }
        if (mych) changed = 1;
        __syncthreads();

        if (changed == 0 || iter == 10) break;

        if (t < 192) {
            float t0 = 0.f, t1 = 0.f, t2 = 0.f, t3 = 0.f;
            for (int kb = 0; kb < C_; kb += BLAS_Q) {
                const int ke = (kb + BLAS_Q < C_) ? (kb + BLAS_Q) : C_;
                float s0 = 0.f, s1 = 0.f, s2 = 0.f, s3 = 0.f;
                for (int c = kb; c < ke; ++c) {
                    const float xv = X[(size_t)c * D_ + t];
                    const int id = ids[c];
                    s0 += (id == 0) ? xv : 0.0f;
                    s1 += (id == 1) ? xv : 0.0f;
                    s2 += (id == 2) ? xv : 0.0f;
                    s3 += (id == 3) ? xv : 0.0f;
                }
                t0 += s0; t1 += s1; t2 += s2; t3 += s3;
            }
            if (cnt[0] > 0) cent[0][t] = t0 / (float)cnt[0];
            if (cnt[1] > 0) cent[1][t] = t1 / (float)cnt[1];
            if (cnt[2] > 0) cent[2][t] = t2 / (float)cnt[2];
            if (cnt[3] > 0) cent[3][t] = t3 / (float)cnt[3];
        }
        __syncthreads();
    }

    for (int c = t; c < C_; c += 512) ids_out[(size_t)b * C_ + c] = ids[c];
}

// ---------------------------------------------------------------------------
__device__ __forceinline__ float bn_apply(float v, float g, float be, float m, float va) {
    return (v - m) / sqrtf(va + EPSf) * g + be;
}

// ---------------------------------------------------------------------------
// Kernel 3: batched 64x64-tiled GEMM, M=256, N=512, K=2048.
// ---------------------------------------------------------------------------
__global__ __launch_bounds__(256) void gemm1_kernel(
    const float* __restrict__ pooled, const unsigned char* __restrict__ ids,
    const float* __restrict__ Wg, const float* __restrict__ bg,
    const float* __restrict__ g_gamma, const float* __restrict__ g_beta,
    const float* __restrict__ g_mean, const float* __restrict__ g_var,
    const float* __restrict__ gb_gamma, const float* __restrict__ gb_beta,
    const float* __restrict__ gb_mean, const float* __restrict__ gb_var,
    const float* __restrict__ W1, const float* __restrict__ b1,
    const float* __restrict__ n1_gamma, const float* __restrict__ n1_beta,
    const float* __restrict__ n1_mean, const float* __restrict__ n1_var,
    float* __restrict__ xg2, float* __restrict__ h1) {
    const int z = blockIdx.z;
    const int bn0 = blockIdx.x * 64, bm0 = blockIdx.y * 64;
    const float* Bmat = (z == 0) ? Wg : W1;
    __shared__ float As[32][68];
    __shared__ float Bs[32][68];
    float acc[4][4] = {};
    const int t = threadIdx.x;
    const int tx = t & 15, ty = t >> 4;

    for (int k0 = 0; k0 < 2048; k0 += 32) {
#pragma unroll
        for (int u = 0; u < 2; ++u) {
            const int idx = t + 256 * u;
            const int m = idx >> 3, kc = idx & 7;
            float4 v = *(const float4*)(pooled + (size_t)(bm0 + m) * 2048 + k0 + kc * 4);
            if (z > 0) {
                const unsigned int uu =
                    *(const unsigned int*)(ids + (size_t)(bm0 + m) * 2048 + k0 + kc * 4);
                const unsigned int k = (unsigned int)(z - 1);
                v.x = ((uu & 0xffu) == k) ? v.x : 0.f;
                v.y = (((uu >> 8) & 0xffu) == k) ? v.y : 0.f;
                v.z = (((uu >> 16) & 0xffu) == k) ? v.z : 0.f;
                v.w = (((uu >> 24) & 0xffu) == k) ? v.w : 0.f;
            }
            As[kc * 4 + 0][m] = v.x; As[kc * 4 + 1][m] = v.y;
            As[kc * 4 + 2][m] = v.z; As[kc * 4 + 3][m] = v.w;
            const float4 wv = *(const float4*)(Bmat + (size_t)(bn0 + m) * 2048 + k0 + kc * 4);
            Bs[kc * 4 + 0][m] = wv.x; Bs[kc * 4 + 1][m] = wv.y;
            Bs[kc * 4 + 2][m] = wv.z; Bs[kc * 4 + 3][m] = wv.w;
        }
        __syncthreads();
#pragma unroll 8
        for (int kk = 0; kk < 32; ++kk) {
            const float4 a = *(const float4*)&As[kk][ty * 4];
            const float4 wv = *(const float4*)&Bs[kk][tx * 4];
            const float av[4] = {a.x, a.y, a.z, a.w};
            const float bv[4] = {wv.x, wv.y, wv.z, wv.w};
#pragma unroll
            for (int i = 0; i < 4; ++i)
#pragma unroll
                for (int j = 0; j < 4; ++j) acc[i][j] += av[i] * bv[j];
        }
        __syncthreads();
    }

    const int m0 = bm0 + ty * 4, n0 = bn0 + tx * 4;
    if (z == 0) {
#pragma unroll
        for (int j = 0; j < 4; ++j) {
            const int n = n0 + j;
            const float bgv = bg[n];
            const float g1 = g_gamma[n], be1 = g_beta[n], mm1 = g_mean[n], vv1 = g_var[n];
            const float g2 = gb_gamma[n], be2 = gb_beta[n], mm2 = gb_mean[n], vv2 = gb_var[n];
#pragma unroll
            for (int i = 0; i < 4; ++i) {
                float v = acc[i][j] + bgv;
                v = bn_apply(v, g1, be1, mm1, vv1);
                v = fmaxf(v, 0.f);
                v = bn_apply(v, g2, be2, mm2, vv2);
                xg2[(size_t)(m0 + i) * 512 + n] = v;
            }
        }
    } else {
        const int k = z - 1;
#pragma unroll
        for (int j = 0; j < 4; ++j) {
            const int n = n0 + j;
            const float b1v = b1[n];
            const float g1 = n1_gamma[n], be1 = n1_beta[n], mm1 = n1_mean[n], vv1 = n1_var[n];
#pragma unroll
            for (int i = 0; i < 4; ++i) {
                float v = acc[i][j] + b1v;
                v = bn_apply(v, g1, be1, mm1, vv1);
                v = fmaxf(v, 0.f);
                h1[((size_t)k * 256 + (m0 + i)) * 512 + n] = v;
            }
        }
    }
}

// ---------------------------------------------------------------------------
// Kernel 4
// ---------------------------------------------------------------------------
__global__ __launch_bounds__(256) void gemm2_kernel(
    const float* __restrict__ h1, const float* __restrict__ W2,
    const float* __restrict__ b2,
    const float* __restrict__ n2_gamma, const float* __restrict__ n2_beta,
    const float* __restrict__ n2_mean, const float* __restrict__ n2_var,
    const float* __restrict__ bk_gamma, const float* __restrict__ bk_beta,
    const float* __restrict__ bk_mean, const float* __restrict__ bk_var,
    float* __restrict__ yv) {
    const int bn0 = blockIdx.x * 64, bm0 = blockIdx.y * 64;
    __shared__ float As[32][68];
    __shared__ float Bs[32][68];
    float acc[4][4] = {};
    const int t = threadIdx.x;
    const int tx = t & 15, ty = t >> 4;

    for (int k0 = 0; k0 < 512; k0 += 32) {
#pragma unroll
        for (int u = 0; u < 2; ++u) {
            const int idx = t + 256 * u;
            const int m = idx >> 3, kc = idx & 7;
            const float4 v = *(const float4*)(h1 + (size_t)(bm0 + m) * 512 + k0 + kc * 4);
            As[kc * 4 + 0][m] = v.x; As[kc * 4 + 1][m] = v.y;
            As[kc * 4 + 2][m] = v.z; As[kc * 4 + 3][m] = v.w;
            const float4 wv = *(const float4*)(W2 + (size_t)(bn0 + m) * 512 + k0 + kc * 4);
            Bs[kc * 4 + 0][m] = wv.x; Bs[kc * 4 + 1][m] = wv.y;
            Bs[kc * 4 + 2][m] = wv.z; Bs[kc * 4 + 3][m] = wv.w;
        }
        __syncthreads();
#pragma unroll 8
        for (int kk = 0; kk < 32; ++kk) {
            const float4 a = *(const float4*)&As[kk][ty * 4];
            const float4 wv = *(const float4*)&Bs[kk][tx * 4];
            const float av[4] = {a.x, a.y, a.z, a.w};
            const float bv[4] = {wv.x, wv.y, wv.z, wv.w};
#pragma unroll
            for (int i = 0; i < 4; ++i)
#pragma unroll
                for (int j = 0; j < 4; ++j) acc[i][j] += av[i] * bv[j];
        }
        __syncthreads();
    }

    const int m0 = bm0 + ty * 4, n0 = bn0 + tx * 4;
#pragma unroll
    for (int j = 0; j < 4; ++j) {
        const int n = n0 + j;
        const float b2v = b2[n];
        const float g1 = n2_gamma[n], be1 = n2_beta[n], mm1 = n2_mean[n], vv1 = n2_var[n];
#pragma unroll
        for (int i = 0; i < 4; ++i) {
            const int row = m0 + i;
            const int k = row >> 8, b = row & 255;
            float v = acc[i][j] + b2v;
            v = bn_apply(v, g1, be1, mm1, vv1);
            v = fmaxf(v, 0.f);
            const int pi = k * 128 + n;
            v = bn_apply(v, bk_gamma[pi], bk_beta[pi], bk_mean[pi], bk_var[pi]);
            yv[(size_t)b * 512 + pi] = v;
        }
    }
}

// ---------------------------------------------------------------------------
// Kernel 5: heads
// ---------------------------------------------------------------------------
__global__ __launch_bounds__(128) void head_kernel(
    const float* __restrict__ xg2, const float* __restrict__ yv,
    const float* __restrict__ Wcg, const float* __restrict__ bcg,
    const float* __restrict__ Wck, const float* __restrict__ bck,
    float* __restrict__ out) {
    const int b = blockIdx.x, t = threadIdx.x;
    __shared__ float xr[512], yr[512];
    ((float4*)xr)[t] = ((const float4*)(xg2 + (size_t)b * 512))[t];
    ((float4*)yr)[t] = ((const float4*)(yv + (size_t)b * 512))[t];
    __syncthreads();
    if (t < 51) {
        float acc = 0.f;
        const float4* wr = (const float4*)(Wcg + (size_t)t * 512);
        const float4* xv = (const float4*)xr;
#pragma unroll 8
        for (int p = 0; p < 128; ++p) {
            const float4 w4 = wr[p], v4 = xv[p];
            acc += w4.x * v4.x + w4.y * v4.y + w4.z * v4.z + w4.w * v4.w;
        }
        out[(size_t)b * 51 + t] = acc + bcg[t];
    } else if (t >= 64 && t < 115) {
        const int n = t - 64;
        float acc = 0.f;
        const float4* wr = (const float4*)(Wck + (size_t)n * 512);
        const float4* yv4 = (const float4*)yr;
#pragma unroll 8
        for (int p = 0; p < 128; ++p) {
            const float4 w4 = wr[p], v4 = yv4[p];
            acc += w4.x * v4.x + w4.y * v4.y + w4.z * v4.z + w4.w * v4.w;
        }
        out[(size_t)(B_ * 51) + (size_t)b * 51 + n] = acc + bck[n];
    }
}

// ---------------------------------------------------------------------------
extern "C" void kernel_launch(void* const* d_in, const int* in_sizes, int n_in,
                              void* d_out, int out_size, void* d_ws, size_t ws_size,
                              hipStream_t stream) {
    const float* x        = (const float*)d_in[0];
    const float* Wg       = (const float*)d_in[1];
    const float* bg       = (const float*)d_in[2];
    const float* g_gamma  = (const float*)d_in[3];
    const float* g_beta   = (const float*)d_in[4];
    const float* g_mean   = (const float*)d_in[5];
    const float* g_var    = (const float*)d_in[6];
    const float* gb_gamma = (const float*)d_in[7];
    const float* gb_beta  = (const float*)d_in[8];
    const float* gb_mean  = (const float*)d_in[9];
    const float* gb_var   = (const float*)d_in[10];
    const float* Wcg      = (const float*)d_in[11];
    const float* bcg      = (const float*)d_in[12];
    const float* W1       = (const float*)d_in[13];
    const float* b1       = (const float*)d_in[14];
    const float* n1_gamma = (const float*)d_in[15];
    const float* n1_beta  = (const float*)d_in[16];
    const float* n1_mean  = (const float*)d_in[17];
    const float* n1_var   = (const float*)d_in[18];
    const float* W2       = (const float*)d_in[19];
    const float* b2       = (const float*)d_in[20];
    const float* n2_gamma = (const float*)d_in[21];
    const float* n2_beta  = (const float*)d_in[22];
    const float* n2_mean  = (const float*)d_in[23];
    const float* n2_var   = (const float*)d_in[24];
    const float* bk_gamma = (const float*)d_in[25];
    const float* bk_beta  = (const float*)d_in[26];
    const float* bk_mean  = (const float*)d_in[27];
    const float* bk_var   = (const float*)d_in[28];
    const float* Wck      = (const float*)d_in[29];
    const float* bck      = (const float*)d_in[30];
    float* out = (float*)d_out;

    const size_t xtp_elems   = (size_t)B_ * D_ * C_PAD;           // padded xT floats
    const size_t small_elems = 524288 * 2 + 131072 + 524288 + 131072; // pooled,xs,xg2,h1,yv
    const size_t need_fast   = xtp_elems * 4 + small_elems * 4 + 524288 + 256;

    if (ws_size >= need_fast) {
        float* xT          = (float*)d_ws;
        float* pooled      = xT + xtp_elems;                     // 524288 f
        float* xs_g        = pooled + 524288;                    // 524288 f
        unsigned char* ids = (unsigned char*)(xs_g + 524288);    // 524288 B
        float* xg2         = (float*)(ids + 524288);             // 131072 f
        float* h1          = xg2 + 131072;                       // 524288 f
        float* yv          = h1 + 524288;                        // 131072 f

        transpose_kernel<<<dim3(32, B_), dim3(256), 0, stream>>>(x, xT, pooled, xs_g);
        kmeans_fast_kernel<<<dim3(B_), dim3(1024), 0, stream>>>(x, xT, xs_g, ids);
        gemm1_kernel<<<dim3(8, 4, 5), dim3(256), 0, stream>>>(
            pooled, ids, Wg, bg, g_gamma, g_beta, g_mean, g_var,
            gb_gamma, gb_beta, gb_mean, gb_var, W1, b1,
            n1_gamma, n1_beta, n1_mean, n1_var, xg2, h1);
        gemm2_kernel<<<dim3(2, 16), dim3(256), 0, stream>>>(
            h1, W2, b2, n2_gamma, n2_beta, n2_mean, n2_var,
            bk_gamma, bk_beta, bk_mean, bk_var, yv);
        head_kernel<<<dim3(B_), dim3(128), 0, stream>>>(xg2, yv, Wcg, bcg, Wck, bck, out);
    } else {
        float* pooled      = (float*)d_ws;                       // 524288 f
        unsigned char* ids = (unsigned char*)(pooled + 524288);  // 524288 B
        float* xg2         = (float*)(ids + 524288);             // 131072 f
        float* h1          = xg2 + 131072;                       // 524288 f
        float* yv          = h1 + 524288;                        // 131072 f

        pool_kernel<<<dim3((B_ * C_) / 4), dim3(256), 0, stream>>>(x, pooled);
        kmeans_fb_kernel<<<dim3(B_), dim3(512), 0, stream>>>(x, ids);
        gemm1_kernel<<<dim3(8, 4, 5), dim3(256), 0, stream>>>(
            pooled, ids, Wg, bg, g_gamma, g_beta, g_mean, g_var,
            gb_gamma, gb_beta, gb_mean, gb_var, W1, b1,
            n1_gamma, n1_beta, n1_mean, n1_var, xg2, h1);
        gemm2_kernel<<<dim3(2, 16), dim3(256), 0, stream>>>(
            h1, W2, b2, n2_gamma, n2_beta, n2_mean, n2_var,
            bk_gamma, bk_beta, bk_mean, bk_var, yv);
        head_kernel<<<dim3(B_), dim3(128), 0, stream>>>(xg2, yv, Wcg, bcg, Wck, bck, out);
    }
}